// Round 6
// baseline (420.467 us; speedup 1.0000x reference)
//
#include <hip/hip_runtime.h>
#include <hip/hip_bf16.h>
#include <math.h>

#define NROWS 65536
#define DIN   512
#define H1    256
#define H2    128
#define K3DIM 384
#define O3    64

typedef short  short8  __attribute__((ext_vector_type(8)));
typedef float  f32x4   __attribute__((ext_vector_type(4)));
typedef unsigned short u16x4 __attribute__((ext_vector_type(4)));

// fp32 -> bf16 bits, round-to-nearest-even
__device__ __forceinline__ unsigned short f2bf(float f) {
    union { float f; unsigned int i; } v; v.f = f;
    unsigned int r = (v.i + 0x7fffu + ((v.i >> 16) & 1u)) >> 16;
    return (unsigned short)r;
}
// bf16 bits -> fp32 (exact)
__device__ __forceinline__ float bf2f(unsigned short u) {
    union { unsigned int i; float f; } v; v.i = ((unsigned int)u) << 16;
    return v.f;
}

// async global->LDS, 16B per lane. lptr must be wave-uniform (HW adds lane*16).
typedef const __attribute__((address_space(1))) unsigned int* gas1_t;
typedef __attribute__((address_space(3))) unsigned int* las3_t;
__device__ __forceinline__ void gload_lds16(const void* g, void* l) {
    __builtin_amdgcn_global_load_lds((gas1_t)g, (las3_t)l, 16, 0, 0);
}

// ---------------------------------------------------------------- K0: all three W -> W^T bf16 (one launch)
__global__ void transpose3_kernel(const float* __restrict__ W1, const float* __restrict__ W2,
                                  const float* __restrict__ W3,
                                  unsigned short* __restrict__ w1t, unsigned short* __restrict__ w2t,
                                  unsigned short* __restrict__ w3t) {
    int idx = blockIdx.x * 256 + threadIdx.x;
    const int n1 = DIN * H1;            // 131072
    const int n2 = H1 * H2;             // 32768
    const int n3 = K3DIM * O3;          // 24576
    if (idx < n1) {
        int c = idx / DIN, r = idx - c * DIN;
        w1t[idx] = f2bf(W1[r * H1 + c]);
    } else if (idx < n1 + n2) {
        int i2 = idx - n1;
        int c = i2 / H1, r = i2 - c * H1;
        w2t[i2] = f2bf(W2[r * H2 + c]);
    } else if (idx < n1 + n2 + n3) {
        int i3 = idx - n1 - n2;
        int c = i3 / K3DIM, r = i3 - c * K3DIM;
        w3t[i3] = f2bf(W3[r * O3 + c]);
    }
}

// ---------------------------------------------------------------- K1: h = x @ W1 + b1 (bf16 out)
// v4 (FROZEN from R2, unmeasured): 2-phase double-buffered K-loop.
#define LDA1 32   // unpadded 64B rows (required for linear global_load_lds dest)

__global__ __launch_bounds__(256, 2)
void gemm1_kernel(const float* __restrict__ x1, const float* __restrict__ x2,
                  const unsigned short* __restrict__ w1t, const float* __restrict__ b1,
                  unsigned short* __restrict__ h_out, float* __restrict__ stats) {
    __shared__ __align__(1024) unsigned short Al[2][64 * LDA1];     // 2 x 4 KB
    __shared__ __align__(1024) unsigned short Bl[2][256 * LDA1];    // 2 x 16 KB
    const int t    = threadIdx.x;
    const int row0 = blockIdx.x * 64;          // 0..131071 across both inputs
    const int inp  = row0 >> 16;               // 0 -> x1 rows, 1 -> x2 rows
    const float* xp = inp ? x2 : x1;
    const int r0 = row0 & (NROWS - 1);

    const int wave = t >> 6, lane = t & 63;    // wave = 64-col slice of H1
    const int m = lane & 15, q = lane >> 4;

    const int bn_local = lane >> 2;            // row within 16-row chunk
    const int bk_off   = (lane & 3) * 8;       // k offset within 32-k tile
    const int ar0 = t >> 3;
    const int ak0 = (t & 7) * 4;

    f32x4 acc[4][4] = {};                      // [mi rows][ni cols]
    float4 va0, va1;

    // ---- prologue: stage tile 0 into buffer 0
#pragma unroll
    for (int i = 0; i < 4; ++i) {
        int chunk = wave * 4 + i;
        gload_lds16(w1t + (size_t)(chunk * 16 + bn_local) * DIN + bk_off, &Bl[0][chunk * 512]);
    }
    va0 = *reinterpret_cast<const float4*>(xp + (size_t)(r0 + ar0) * DIN + ak0);
    va1 = *reinterpret_cast<const float4*>(xp + (size_t)(r0 + ar0 + 32) * DIN + ak0);
    {
        u16x4 c0; c0.x = f2bf(va0.x); c0.y = f2bf(va0.y); c0.z = f2bf(va0.z); c0.w = f2bf(va0.w);
        u16x4 c1; c1.x = f2bf(va1.x); c1.y = f2bf(va1.y); c1.z = f2bf(va1.z); c1.w = f2bf(va1.w);
        *reinterpret_cast<u16x4*>(&Al[0][ar0 * LDA1 + ak0])        = c0;
        *reinterpret_cast<u16x4*>(&Al[0][(ar0 + 32) * LDA1 + ak0]) = c1;
    }
    __syncthreads();

    // ---- main loop: one barrier per K-step
#pragma unroll
    for (int kt = 0; kt < 16; ++kt) {
        const int d = kt & 1;
        if (kt < 15) {
            const int kn = (kt + 1) * 32;
#pragma unroll
            for (int i = 0; i < 4; ++i) {
                int chunk = wave * 4 + i;
                gload_lds16(w1t + (size_t)(chunk * 16 + bn_local) * DIN + kn + bk_off,
                            &Bl[d ^ 1][chunk * 512]);
            }
            va0 = *reinterpret_cast<const float4*>(xp + (size_t)(r0 + ar0) * DIN + kn + ak0);
            va1 = *reinterpret_cast<const float4*>(xp + (size_t)(r0 + ar0 + 32) * DIN + kn + ak0);
        }
        short8 af[4], bfr[4];
#pragma unroll
        for (int mi = 0; mi < 4; ++mi)
            af[mi] = *reinterpret_cast<const short8*>(&Al[d][(mi * 16 + m) * LDA1 + q * 8]);
#pragma unroll
        for (int ni = 0; ni < 4; ++ni)
            bfr[ni] = *reinterpret_cast<const short8*>(&Bl[d][(wave * 64 + ni * 16 + m) * LDA1 + q * 8]);
#pragma unroll
        for (int mi = 0; mi < 4; ++mi)
#pragma unroll
            for (int ni = 0; ni < 4; ++ni)
                acc[mi][ni] = __builtin_amdgcn_mfma_f32_16x16x32_bf16(af[mi], bfr[ni], acc[mi][ni], 0, 0, 0);
        if (kt < 15) {
            u16x4 c0; c0.x = f2bf(va0.x); c0.y = f2bf(va0.y); c0.z = f2bf(va0.z); c0.w = f2bf(va0.w);
            u16x4 c1; c1.x = f2bf(va1.x); c1.y = f2bf(va1.y); c1.z = f2bf(va1.z); c1.w = f2bf(va1.w);
            *reinterpret_cast<u16x4*>(&Al[d ^ 1][ar0 * LDA1 + ak0])        = c0;
            *reinterpret_cast<u16x4*>(&Al[d ^ 1][(ar0 + 32) * LDA1 + ak0]) = c1;
        }
        __syncthreads();
    }

    // epilogue: h store + fused column sum / sumsq (stats on fp32 pre-rounding h)
#pragma unroll
    for (int ni = 0; ni < 4; ++ni) {
        const int col = wave * 64 + ni * 16 + m;
        const float bias = b1[col];
        float s = 0.f, ssq = 0.f;
#pragma unroll
        for (int mi = 0; mi < 4; ++mi) {
#pragma unroll
            for (int r = 0; r < 4; ++r) {
                int row = row0 + mi * 16 + q * 4 + r;
                float v = acc[mi][ni][r] + bias;
                h_out[(size_t)row * H1 + col] = f2bf(v);
                s += v; ssq += v * v;
            }
        }
        s   += __shfl_xor(s, 16);   s   += __shfl_xor(s, 32);
        ssq += __shfl_xor(ssq, 16); ssq += __shfl_xor(ssq, 32);
        if (q == 0) {
            atomicAdd(&stats[(inp * 2 + 0) * H1 + col], s);
            atomicAdd(&stats[(inp * 2 + 1) * H1 + col], ssq);
        }
    }
}

// ---------------------------------------------------------------- K2b: BN -> per-column affine
__global__ void bnparams_kernel(const float* __restrict__ stats, const float* __restrict__ gamma,
                                const float* __restrict__ beta_bn, float* __restrict__ ab) {
    int t = threadIdx.x;                // 512
    int inp = t >> 8, c = t & 255;
    float mean = stats[(inp * 2 + 0) * H1 + c] * (1.0f / NROWS);
    float ex2  = stats[(inp * 2 + 1) * H1 + c] * (1.0f / NROWS);
    float var  = ex2 - mean * mean;
    float a = gamma[c] * rsqrtf(var + 1e-5f);
    ab[(inp * 2 + 0) * H1 + c] = a;
    ab[(inp * 2 + 1) * H1 + c] = beta_bn[c] - a * mean;
}

// ---------------------------------------------------------------- K3a: z = relu(relu(BN(h)) @ W2 + b2)
// v4: B2 LDS tile ELIMINATED (W2^T is 64KB, L2-resident -> direct global
// B-fragment reads w/ register prefetch). Al double-buffered -> 1 barrier/K-step.
// LDS 80KB -> 22KB (occupancy cap 2 -> 3+ blocks/CU).
#define LDA  40

__global__ __launch_bounds__(256, 2)
void gemm2_kernel(const unsigned short* __restrict__ h, const unsigned short* __restrict__ w2t,
                  const float* __restrict__ b2, const float* __restrict__ ab,
                  unsigned short* __restrict__ z) {
    __shared__ __align__(16) unsigned short Al[2][128 * LDA];   // 2 x 10 KB
    __shared__ float sc[H1], sh[H1];
    const int t  = threadIdx.x;
    const int m0 = blockIdx.x * 128;
    const int inp = m0 >> 16;
    sc[t] = ab[(inp * 2 + 0) * H1 + t];
    sh[t] = ab[(inp * 2 + 1) * H1 + t];

    const int wave = t >> 6, lane = t & 63;
    const int wm = wave >> 1, wn = wave & 1;
    const int m = lane & 15, q = lane >> 4;
    const int ar = t >> 1, akh = (t & 1) * 16;   // A-stage mapping: 16 bf16 per thread
    const unsigned short* hrow = h + (size_t)(m0 + ar) * H1 + akh;

    f32x4 acc[4][4] = {};
    short8 bcur[4], bnext[4];
    float4 ha0, ha1;

    // prologue: loads for kt=0
    ha0 = *reinterpret_cast<const float4*>(hrow);
    ha1 = *reinterpret_cast<const float4*>(hrow + 8);
#pragma unroll
    for (int ni = 0; ni < 4; ++ni)
        bcur[ni] = *reinterpret_cast<const short8*>(w2t + (size_t)(wn * 64 + ni * 16 + m) * H1 + q * 8);
    __syncthreads();   // sc/sh visible
    {   // conv kt=0 into Al[0]
        unsigned short vs[16] __attribute__((aligned(16)));
        unsigned short ob[16] __attribute__((aligned(16)));
        *reinterpret_cast<float4*>(vs)     = ha0;
        *reinterpret_cast<float4*>(vs + 8) = ha1;
#pragma unroll
        for (int j = 0; j < 16; ++j) {
            float v = sc[akh + j] * bf2f(vs[j]) + sh[akh + j];
            ob[j] = f2bf(fmaxf(v, 0.f));
        }
        *reinterpret_cast<float4*>(&Al[0][ar * LDA + akh])     = *reinterpret_cast<float4*>(ob);
        *reinterpret_cast<float4*>(&Al[0][ar * LDA + akh + 8]) = *reinterpret_cast<float4*>(ob + 8);
    }
    __syncthreads();   // Al[0] published

#pragma unroll
    for (int kt = 0; kt < 8; ++kt) {
        const int d = kt & 1;
        if (kt < 7) {   // issue kt+1 loads: A -> regs, B-frags -> regs (L2-hot)
            const int kn = (kt + 1) * 32;
            ha0 = *reinterpret_cast<const float4*>(hrow + kn);
            ha1 = *reinterpret_cast<const float4*>(hrow + kn + 8);
#pragma unroll
            for (int ni = 0; ni < 4; ++ni)
                bnext[ni] = *reinterpret_cast<const short8*>(
                    w2t + (size_t)(wn * 64 + ni * 16 + m) * H1 + kn + q * 8);
        }
        // MFMA on current buffer + current B-frags
        short8 af[4];
#pragma unroll
        for (int mi = 0; mi < 4; ++mi)
            af[mi] = *reinterpret_cast<const short8*>(&Al[d][(wm * 64 + mi * 16 + m) * LDA + q * 8]);
#pragma unroll
        for (int mi = 0; mi < 4; ++mi)
#pragma unroll
            for (int ni = 0; ni < 4; ++ni)
                acc[mi][ni] = __builtin_amdgcn_mfma_f32_16x16x32_bf16(af[mi], bcur[ni], acc[mi][ni], 0, 0, 0);
        // conv kt+1 into the other buffer (vmcnt wait for ha lands here, after MFMAs)
        if (kt < 7) {
            const int kn = (kt + 1) * 32;
            unsigned short vs[16] __attribute__((aligned(16)));
            unsigned short ob[16] __attribute__((aligned(16)));
            *reinterpret_cast<float4*>(vs)     = ha0;
            *reinterpret_cast<float4*>(vs + 8) = ha1;
#pragma unroll
            for (int j = 0; j < 16; ++j) {
                int k = kn + akh + j;
                float v = sc[k] * bf2f(vs[j]) + sh[k];
                ob[j] = f2bf(fmaxf(v, 0.f));
            }
            *reinterpret_cast<float4*>(&Al[d ^ 1][ar * LDA + akh])     = *reinterpret_cast<float4*>(ob);
            *reinterpret_cast<float4*>(&Al[d ^ 1][ar * LDA + akh + 8]) = *reinterpret_cast<float4*>(ob + 8);
#pragma unroll
            for (int ni = 0; ni < 4; ++ni) bcur[ni] = bnext[ni];
        }
        __syncthreads();
    }
#pragma unroll
    for (int mi = 0; mi < 4; ++mi)
#pragma unroll
        for (int ni = 0; ni < 4; ++ni) {
            int col = wn * 64 + ni * 16 + m;
            float bias = b2[col];
#pragma unroll
            for (int r = 0; r < 4; ++r) {
                int row = m0 + wm * 64 + mi * 16 + q * 4 + r;
                z[(size_t)row * H2 + col] = f2bf(fmaxf(acc[mi][ni][r] + bias, 0.f));
            }
        }
}

// ---------------------------------------------------------------- K4: head (cosine + MLP + blend)
// v2: W3 LDS staging removed (48KB, L2-broadcast across 512 blocks) ->
// direct global fragment reads. LDS ~120KB -> ~71KB (1 -> 2 blocks/CU).
#define LDZ  136

__global__ __launch_bounds__(512, 2)
void head_kernel(const unsigned short* __restrict__ z, const unsigned short* __restrict__ w3t,
                 const float* __restrict__ b3, const float* __restrict__ w4,
                 const float* __restrict__ b4, const float* __restrict__ alpha,
                 const float* __restrict__ beta, float* __restrict__ out) {
    __shared__ __align__(16) unsigned short Z1[128 * LDZ];
    __shared__ __align__(16) unsigned short Z2[128 * LDZ];
    __shared__ float b3s[64], w4s[64];
    __shared__ float smath[128], slearn[128];

    const int t  = threadIdx.x;        // 512
    const int r0 = blockIdx.x * 128;

    {   // stage z1/z2 tiles: 128 rows x 128 bf16 each
        int r = t >> 2, seg = t & 3;
        const float4* f1 = reinterpret_cast<const float4*>(z + (size_t)(r0 + r) * H2 + seg * 32);
        const float4* f2 = reinterpret_cast<const float4*>(z + (size_t)(NROWS + r0 + r) * H2 + seg * 32);
        float4* d1 = reinterpret_cast<float4*>(&Z1[r * LDZ + seg * 32]);
        float4* d2 = reinterpret_cast<float4*>(&Z2[r * LDZ + seg * 32]);
        d1[0] = f1[0]; d1[1] = f1[1]; d1[2] = f1[2]; d1[3] = f1[3];
        d2[0] = f2[0]; d2[1] = f2[1]; d2[2] = f2[2]; d2[3] = f2[3];
    }
    if (t < 64) { b3s[t] = b3[t]; w4s[t] = w4[t]; }
    __syncthreads();

    {   // cosine: 4 threads per row
        int r = t >> 2, part = t & 3;
        float d = 0.f, s1 = 0.f, s2 = 0.f;
#pragma unroll
        for (int j = 0; j < 32; ++j) {
            int k = part * 32 + j;
            float a = bf2f(Z1[r * LDZ + k]);
            float b = bf2f(Z2[r * LDZ + k]);
            d += a * b; s1 += a * a; s2 += b * b;
        }
        d  += __shfl_xor(d, 1);  d  += __shfl_xor(d, 2);
        s1 += __shfl_xor(s1, 1); s1 += __shfl_xor(s1, 2);
        s2 += __shfl_xor(s2, 1); s2 += __shfl_xor(s2, 2);
        if (part == 0) {
            float inv1 = 1.f / fmaxf(sqrtf(s1), 1e-15f);
            float inv2 = 1.f / fmaxf(sqrtf(s2), 1e-15f);
            float sm = d * inv1 * inv2;
            smath[r] = fminf(fmaxf(sm, 0.f), 1.f);
        }
    }

    // MFMA over combined = [z1*z2 | |z1-z2| | z1+z2] @ W3 (B-frags direct from L2)
    const int wave = t >> 6, lane = t & 63;
    const int m = lane & 15, q = lane >> 4;
    const int wr = wave * 16;
    f32x4 acc[4] = {};
#pragma unroll
    for (int kb = 0; kb < 12; ++kb) {
        int seg = kb >> 2;
        int kl  = (kb & 3) * 32 + q * 8;
        short8 a1 = *reinterpret_cast<const short8*>(&Z1[(wr + m) * LDZ + kl]);
        short8 a2 = *reinterpret_cast<const short8*>(&Z2[(wr + m) * LDZ + kl]);
        short8 af;
#pragma unroll
        for (int j = 0; j < 8; ++j) {
            float v1 = bf2f((unsigned short)a1[j]);
            float v2 = bf2f((unsigned short)a2[j]);
            float v = (seg == 0) ? v1 * v2 : (seg == 1 ? fabsf(v1 - v2) : v1 + v2);
            af[j] = (short)f2bf(v);
        }
#pragma unroll
        for (int ni = 0; ni < 4; ++ni) {
            short8 bfr = *reinterpret_cast<const short8*>(
                w3t + (size_t)(ni * 16 + m) * K3DIM + kb * 32 + q * 8);
            acc[ni] = __builtin_amdgcn_mfma_f32_16x16x32_bf16(af, bfr, acc[ni], 0, 0, 0);
        }
    }
    float partial[4] = {0.f, 0.f, 0.f, 0.f};
#pragma unroll
    for (int ni = 0; ni < 4; ++ni) {
        int col = ni * 16 + m;
        float bias = b3s[col], w4v = w4s[col];
#pragma unroll
        for (int rg = 0; rg < 4; ++rg) {
            float v = fmaxf(acc[ni][rg] + bias, 0.f);
            partial[rg] += v * w4v;
        }
    }
#pragma unroll
    for (int rg = 0; rg < 4; ++rg) {
        float p = partial[rg];
        p += __shfl_xor(p, 1); p += __shfl_xor(p, 2);
        p += __shfl_xor(p, 4); p += __shfl_xor(p, 8);
        if (m == 0) slearn[wr + q * 4 + rg] = p + b4[0];
    }
    __syncthreads();
    if (t < 128) {
        float sl = slearn[t];
        float sig = 1.f / (1.f + expf(-sl));
        float f = alpha[0] * smath[t] + beta[0] * sig;
        out[r0 + t] = fminf(fmaxf(f, 0.f), 1.f);
    }
}

// ---------------------------------------------------------------- launch
extern "C" void kernel_launch(void* const* d_in, const int* in_sizes, int n_in,
                              void* d_out, int out_size, void* d_ws, size_t ws_size,
                              hipStream_t stream) {
    (void)in_sizes; (void)n_in; (void)out_size; (void)ws_size;
    const float* x1      = (const float*)d_in[0];
    const float* x2      = (const float*)d_in[1];
    const float* W1      = (const float*)d_in[2];
    const float* b1      = (const float*)d_in[3];
    const float* gamma   = (const float*)d_in[4];
    const float* beta_bn = (const float*)d_in[5];
    const float* W2      = (const float*)d_in[6];
    const float* b2      = (const float*)d_in[7];
    const float* W3      = (const float*)d_in[8];
    const float* b3      = (const float*)d_in[9];
    const float* W4      = (const float*)d_in[10];
    const float* b4      = (const float*)d_in[11];
    const float* alpha   = (const float*)d_in[12];
    const float* beta    = (const float*)d_in[13];
    float* out = (float*)d_out;

    char* ws = (char*)d_ws;
    unsigned short* h   = (unsigned short*)(ws);                  // 2*65536*256*2 = 67108864 B
    unsigned short* w1t = (unsigned short*)(ws + 67108864);       // 262144 B
    unsigned short* w2t = (unsigned short*)(ws + 67371008);       // 65536 B
    unsigned short* w3t = (unsigned short*)(ws + 67436544);       // 49152 B
    float*          stats = (float*)(ws + 67485696);              // 4096 B
    float*          ab    = (float*)(ws + 67489792);              // 4096 B
    unsigned short* z   = (unsigned short*)(ws + 67493888);       // 33554432 B

    (void)hipMemsetAsync(stats, 0, 4096, stream);
    transpose3_kernel<<<(DIN * H1 + H1 * H2 + K3DIM * O3 + 255) / 256, 256, 0, stream>>>(
        W1, W2, W3, w1t, w2t, w3t);
    gemm1_kernel<<<2048, 256, 0, stream>>>(x1, x2, w1t, b1, h, stats);
    bnparams_kernel<<<1, 512, 0, stream>>>(stats, gamma, beta_bn, ab);
    gemm2_kernel<<<1024, 256, 0, stream>>>(h, w2t, b2, ab, z);
    head_kernel<<<512, 512, 0, stream>>>(z, w3t, b3, W4, b4, alpha, beta, out);
}